// Round 2
// baseline (54.454 us; speedup 1.0000x reference)
//
#include <hip/hip_runtime.h>
#include <climits>

// Problem constants
#define VV 50257
#define DD 1024
#define BB 16
#define SS 2048
#define PP 10
#define AA 5
#define TT 64
#define LL (PP + SS + TT + AA)   // 2127

// Output element offsets (float32 elements, outputs concatenated flat in return order)
#define OFF_EMB ((size_t)0)
#define OFF_AM  ((size_t)BB * LL * DD)
#define OFF_TM  (OFF_AM + (size_t)BB * LL)
#define OFF_TI  (OFF_TM + (size_t)BB * LL)
#define OFF_S2  (OFF_TI + (size_t)BB * TT)
#define OFF_LAB (OFF_S2 + (size_t)BB)

// Kernel 1: per-batch split computation + all small outputs (f32)
__global__ void soft_emb_small(const int* __restrict__ attn_mask,   // (B,S)
                               const int* __restrict__ tgt_ids,     // (B,T)
                               const int* __restrict__ tgt_am,      // (B,T)
                               float* __restrict__ out,             // f32 flat
                               int* __restrict__ ws_split)          // (B,) scratch
{
    const int b = blockIdx.x;
    const int tid = threadIdx.x;
    __shared__ int red[256];

    // first zero index of attention_mask[b]
    const int* mrow = attn_mask + (size_t)b * SS;
    int fz = INT_MAX;
    for (int j = tid; j < SS; j += 256)
        if (mrow[j] == 0) fz = min(fz, j);
    red[tid] = fz;
    __syncthreads();
    for (int o = 128; o > 0; o >>= 1) {
        if (tid < o) red[tid] = min(red[tid], red[tid + o]);
        __syncthreads();
    }
    const int first0 = red[0];
    // argmax(1-am) over am=[ones(P), mask]: P+first0 if a zero exists, else 0. split = that + 1.
    const int s  = (first0 == INT_MAX) ? 1 : (PP + first0 + 1);
    const int s2 = s + AA;

    if (tid == 0) {
        ws_split[b] = s;
        out[OFF_S2 + b] = (float)s2;
    }

    const int* trow  = tgt_ids + (size_t)b * TT;
    const int* tmrow = tgt_am  + (size_t)b * TT;
    float* amo  = out + OFF_AM  + (size_t)b * LL;
    float* tmo  = out + OFF_TM  + (size_t)b * LL;
    float* labo = out + OFF_LAB + (size_t)b * LL;

    for (int j = tid; j < LL; j += 256) {
        // ---- am (after both inserts at split) ----
        float amv;
        if (j < s) {
            amv = (j < PP) ? 1.0f : (float)mrow[j - PP];
        } else if (j < s2) {
            amv = 1.0f;                              // appended ones
        } else if (j < s2 + TT) {
            amv = (float)tmrow[j - s2];              // target attention mask
        } else {
            int k = j - AA - TT;
            amv = (k < PP) ? 1.0f : (float)mrow[k - PP];
        }
        amo[j] = amv;

        // ---- target_mask, shifted right by 1 ----
        float tmv = 0.0f;
        if (j > 0) {
            int k = j - 1 - s2;
            if (k >= 0 && k < TT) tmv = (float)tmrow[k];
        }
        tmo[j] = tmv;

        // ---- labels, shifted left by 1 (last = -1) ----
        float lv = -1.0f;
        if (j < LL - 1) {
            int u = j + 1 - s2;
            if (u >= 0 && u < TT && tmrow[u] == 1) lv = (float)trow[u];
        }
        labo[j] = lv;
    }

    // ---- target_ids: input shifted left by 1, last = -1 ----
    if (tid < TT) {
        float tv = (tid == TT - 1) ? -1.0f : (float)trow[tid + 1];
        out[OFF_TI + (size_t)b * TT + tid] = tv;
    }
}

// Kernel 2: one block per output emb row; float4 gather -> float4 store
__global__ void soft_emb_rows(const int* __restrict__ input_ids,  // (B,S)
                              const int* __restrict__ tgt_ids,    // (B,T)
                              const float* __restrict__ wte,      // (V,D)
                              const float* __restrict__ prep,     // (P,D)
                              const float* __restrict__ app,      // (A,D)
                              const int* __restrict__ ws_split,   // (B,)
                              float* __restrict__ out)            // f32 flat
{
    const int j = blockIdx.x;        // row in [0, LL)
    const int b = blockIdx.y;        // batch
    const int tid = threadIdx.x;     // 256 threads x float4 = 1024 floats = DD
    const int s = ws_split[b];

    const float* src;
    if (j < s) {
        src = (j < PP) ? (prep + (size_t)j * DD)
                       : (wte + (size_t)input_ids[(size_t)b * SS + (j - PP)] * DD);
    } else if (j < s + AA) {
        src = app + (size_t)(j - s) * DD;
    } else if (j < s + AA + TT) {
        src = wte + (size_t)tgt_ids[(size_t)b * TT + (j - s - AA)] * DD;
    } else {
        int k = j - AA - TT;
        src = (k < PP) ? (prep + (size_t)k * DD)
                       : (wte + (size_t)input_ids[(size_t)b * SS + (k - PP)] * DD);
    }

    float4 v = reinterpret_cast<const float4*>(src)[tid];
    reinterpret_cast<float4*>(out + OFF_EMB + ((size_t)b * LL + j) * DD)[tid] = v;
}

extern "C" void kernel_launch(void* const* d_in, const int* in_sizes, int n_in,
                              void* d_out, int out_size, void* d_ws, size_t ws_size,
                              hipStream_t stream) {
    const int*   input_ids = (const int*)d_in[0];
    const int*   attn_mask = (const int*)d_in[1];
    const int*   tgt_ids   = (const int*)d_in[2];
    const int*   tgt_am    = (const int*)d_in[3];
    const float* wte       = (const float*)d_in[4];
    const float* prep      = (const float*)d_in[5];
    const float* app       = (const float*)d_in[6];
    float* out = (float*)d_out;
    int* ws = (int*)d_ws;

    soft_emb_small<<<BB, 256, 0, stream>>>(attn_mask, tgt_ids, tgt_am, out, ws);
    soft_emb_rows<<<dim3(LL, BB), 256, 0, stream>>>(input_ids, tgt_ids, wte, prep, app, ws, out);
}

// Round 3
// 52.750 us; speedup vs baseline: 1.0323x; 1.0323x over previous
//
#include <hip/hip_runtime.h>
#include <climits>

// Problem constants
#define VV 50257
#define DD 1024
#define BB 16
#define SS 2048
#define PP 10
#define AA 5
#define TT 64
#define LL (PP + SS + TT + AA)   // 2127

// Output element offsets (float32 elements, outputs concatenated flat in return order)
#define OFF_EMB ((size_t)0)
#define OFF_AM  ((size_t)BB * LL * DD)
#define OFF_TM  (OFF_AM + (size_t)BB * LL)
#define OFF_TI  (OFF_TM + (size_t)BB * LL)
#define OFF_S2  (OFF_TI + (size_t)BB * TT)
#define OFF_LAB (OFF_S2 + (size_t)BB)

typedef float f4 __attribute__((ext_vector_type(4)));

// Kernel 1: per-batch split computation ONLY (fast, 16 blocks)
__global__ void soft_emb_split(const int* __restrict__ attn_mask,   // (B,S)
                               int* __restrict__ ws_split)          // (B,)
{
    const int b = blockIdx.x;
    const int tid = threadIdx.x;
    __shared__ int red[256];

    const int* mrow = attn_mask + (size_t)b * SS;
    int fz = INT_MAX;
    for (int j = tid; j < SS; j += 256)
        if (mrow[j] == 0) fz = min(fz, j);
    red[tid] = fz;
    __syncthreads();
    for (int o = 128; o > 0; o >>= 1) {
        if (tid < o) red[tid] = min(red[tid], red[tid + o]);
        __syncthreads();
    }
    if (tid == 0) {
        const int first0 = red[0];
        ws_split[b] = (first0 == INT_MAX) ? 1 : (PP + first0 + 1);
    }
}

// Kernel 2: grid (LL+1, BB).
//  blockIdx.x <  LL : copy one emb row (float4 gather -> nontemporal float4 store)
//  blockIdx.x == LL : all small outputs for batch b (overlaps with row copies)
__global__ void soft_emb_main(const int* __restrict__ input_ids,  // (B,S)
                              const int* __restrict__ attn_mask,  // (B,S)
                              const int* __restrict__ tgt_ids,    // (B,T)
                              const int* __restrict__ tgt_am,     // (B,T)
                              const float* __restrict__ wte,      // (V,D)
                              const float* __restrict__ prep,     // (P,D)
                              const float* __restrict__ app,      // (A,D)
                              const int* __restrict__ ws_split,   // (B,)
                              float* __restrict__ out)            // f32 flat
{
    const int j = blockIdx.x;
    const int b = blockIdx.y;
    const int tid = threadIdx.x;
    const int s = ws_split[b];
    const int s2 = s + AA;

    if (j < LL) {
        // ---- emb row copy ----
        const float* src;
        if (j < s) {
            src = (j < PP) ? (prep + (size_t)j * DD)
                           : (wte + (size_t)input_ids[(size_t)b * SS + (j - PP)] * DD);
        } else if (j < s2) {
            src = app + (size_t)(j - s) * DD;
        } else if (j < s2 + TT) {
            src = wte + (size_t)tgt_ids[(size_t)b * TT + (j - s2)] * DD;
        } else {
            int k = j - AA - TT;
            src = (k < PP) ? (prep + (size_t)k * DD)
                           : (wte + (size_t)input_ids[(size_t)b * SS + (k - PP)] * DD);
        }
        f4 v = reinterpret_cast<const f4*>(src)[tid];
        f4* dst = reinterpret_cast<f4*>(out + OFF_EMB + ((size_t)b * LL + j) * DD) + tid;
        __builtin_nontemporal_store(v, dst);
        return;
    }

    // ---- small outputs for batch b ----
    const int* mrow  = attn_mask + (size_t)b * SS;
    const int* trow  = tgt_ids   + (size_t)b * TT;
    const int* tmrow = tgt_am    + (size_t)b * TT;
    float* amo  = out + OFF_AM  + (size_t)b * LL;
    float* tmo  = out + OFF_TM  + (size_t)b * LL;
    float* labo = out + OFF_LAB + (size_t)b * LL;

    for (int i = tid; i < LL; i += 256) {
        // ---- am (after both inserts at split) ----
        float amv;
        if (i < s) {
            amv = (i < PP) ? 1.0f : (float)mrow[i - PP];
        } else if (i < s2) {
            amv = 1.0f;                              // appended ones
        } else if (i < s2 + TT) {
            amv = (float)tmrow[i - s2];              // target attention mask
        } else {
            int k = i - AA - TT;
            amv = (k < PP) ? 1.0f : (float)mrow[k - PP];
        }
        amo[i] = amv;

        // ---- target_mask, shifted right by 1 ----
        float tmv = 0.0f;
        if (i > 0) {
            int k = i - 1 - s2;
            if (k >= 0 && k < TT) tmv = (float)tmrow[k];
        }
        tmo[i] = tmv;

        // ---- labels, shifted left by 1 (last = -1) ----
        float lv = -1.0f;
        if (i < LL - 1) {
            int u = i + 1 - s2;
            if (u >= 0 && u < TT && tmrow[u] == 1) lv = (float)trow[u];
        }
        labo[i] = lv;
    }

    // ---- target_ids: input shifted left by 1, last = -1; and split2 ----
    if (tid < TT) {
        float tv = (tid == TT - 1) ? -1.0f : (float)trow[tid + 1];
        out[OFF_TI + (size_t)b * TT + tid] = tv;
    }
    if (tid == 0) out[OFF_S2 + b] = (float)s2;
}

extern "C" void kernel_launch(void* const* d_in, const int* in_sizes, int n_in,
                              void* d_out, int out_size, void* d_ws, size_t ws_size,
                              hipStream_t stream) {
    const int*   input_ids = (const int*)d_in[0];
    const int*   attn_mask = (const int*)d_in[1];
    const int*   tgt_ids   = (const int*)d_in[2];
    const int*   tgt_am    = (const int*)d_in[3];
    const float* wte       = (const float*)d_in[4];
    const float* prep      = (const float*)d_in[5];
    const float* app       = (const float*)d_in[6];
    float* out = (float*)d_out;
    int* ws = (int*)d_ws;

    soft_emb_split<<<BB, 256, 0, stream>>>(attn_mask, ws);
    soft_emb_main<<<dim3(LL + 1, BB), 256, 0, stream>>>(input_ids, attn_mask, tgt_ids, tgt_am,
                                                        wte, prep, app, ws, out);
}